// Round 12
// baseline (279.925 us; speedup 1.0000x reference)
//
#include <hip/hip_runtime.h>
#include <stdint.h>

// Problem constants
#define N_POINTS   34100
#define BATCH      8
#define N_GT       200
#define NLEV       5
#define NCAND      3500
#define MAX_DET    300
#define SCORE_TH   0.05f
#define NMS_TH     0.5f
#define IMG        1280.0f
#define NBIN       4096
#define TIE_CAP    4096
// Exact threshold: RN(inter/denom) > 0.5  <=>  inter > T, T=(0.5+2^-25)*denom
// f32 fast path + f64 boundary fallback (R11-verified, absmax 0).
#define MTH 0.50000002980232238769531250

// Output layout (float32 flat, reference return order)
#define OUT_MATCH  0        // 8*34100
#define OUT_BOXES  272800   // 8*300*4
#define OUT_SCORES 282400   // 8*300
#define OUT_LABELS 284800   // 8*300
#define OUT_VALID  287200   // 8*300

// Workspace layout (bytes) — keys array retired (R12)
#define WS_SBOX    2632192        // float4[8*3500] =   448,000
#define WS_SSC     3080192        // float[8*3500]  =   112,000
#define WS_MASK    3192192        // u64[8*98560]   = 6,307,840
#define WS_DIAG    9500032        // u64[8*3520]    =   225,280
#define MASK_STRIDE 98560
#define DIAG_STRIDE 3520

typedef unsigned long long u64;
typedef uint32_t u32;

// Packed upper-triangle row offset: row c stores words (c>>6)..54
__device__ __forceinline__ int mask_off(int c) {
    int g = c >> 6;
    return 64 * (55 * g - (g * (g - 1)) / 2) + (c - (g << 6)) * (55 - g);
}

__device__ __forceinline__ int level_of(int p) {
    return (p < 25600) ? 0 : (p < 32000) ? 1 : (p < 33600) ? 2 : (p < 34000) ? 3 : 4;
}
__device__ __forceinline__ int loff_of(int l) {
    return (l == 0) ? 0 : (l == 1) ? 25600 : (l == 2) ? 32000 : (l == 3) ? 33600 : 34000;
}
__device__ __forceinline__ int k_of(int l) {
    return (l == 0) ? 1000 : (l == 1) ? 1000 : (l == 2) ? 1000 : (l == 3) ? 400 : 100;
}
__device__ __forceinline__ u64 readlane64(u64 v, int t) {
    u32 lo = (u32)__builtin_amdgcn_readlane((int)(u32)v, t);
    u32 hi = (u32)__builtin_amdgcn_readlane((int)(u32)(v >> 32), t);
    return ((u64)hi << 32) | lo;
}
__device__ __forceinline__ u32 sigkey(float lg) {
    float s = 1.0f / (1.0f + expf(-lg));
    u32 u = __float_as_uint(s);
    return (u & 0x80000000u) ? ~u : (u | 0x80000000u);
}

// ---------------------------------------------------------------------------
// Kernel 1: point->gt matching only (R12: key computation moved to pipeline).
// ---------------------------------------------------------------------------
#define MPT 2
__global__ __launch_bounds__(256)
void match_kernel(const float* __restrict__ points,
                  const float* __restrict__ gt,
                  float* __restrict__ out_match) {
#pragma clang fp contract(off)
    __shared__ float bx1[N_GT], by1[N_GT], bx2[N_GT], by2[N_GT], ar[N_GT];
    const int b = blockIdx.y;
    const int base = blockIdx.x * (256 * MPT) + threadIdx.x;

    for (int j = threadIdx.x; j < N_GT; j += 256) {
        float x1 = gt[(b * N_GT + j) * 4 + 0];
        float y1 = gt[(b * N_GT + j) * 4 + 1];
        float x2 = gt[(b * N_GT + j) * 4 + 2];
        float y2 = gt[(b * N_GT + j) * 4 + 3];
        bx1[j] = x1; by1[j] = y1; bx2[j] = x2; by2[j] = y2;
        ar[j] = (x2 - x1) * (y2 - y1);
    }
    __syncthreads();

    const float BIGF = 2147483648.0f;   // float32(2^31-1) rounds to 2^31
    float px[MPT], py[MPT], best[MPT];
    int bi[MPT];
#pragma unroll
    for (int k = 0; k < MPT; ++k) {
        int p = base + k * 256;
        int pc = (p < N_POINTS) ? p : 0;
        px[k] = points[pc * 2 + 0];
        py[k] = points[pc * 2 + 1];
        best[k] = BIGF; bi[k] = -1;
    }
    for (int j = 0; j < N_GT; ++j) {
        float x1 = bx1[j], y1 = by1[j], x2 = bx2[j], y2 = by2[j], a = ar[j];
#pragma unroll
        for (int k = 0; k < MPT; ++k) {
            bool inside = (px[k] >= x1) && (px[k] <= x2) &&
                          (py[k] >= y1) && (py[k] <= y2);
            float cost = inside ? a : BIGF;
            if (cost < best[k]) { best[k] = cost; bi[k] = j; }   // strict <
        }
    }
#pragma unroll
    for (int k = 0; k < MPT; ++k) {
        int p = base + k * 256;
        if (p < N_POINTS) out_match[b * N_POINTS + p] = (float)bi[k];
    }
}

// ---------------------------------------------------------------------------
// Kernel 2: R12 pipeline — single-pass phases:
//   A: one pass over 34100 logits -> sigmoid keys -> 5 level-histograms (LDS)
//   B: 5 threshold selects in PARALLEL (waves 0..4)
//   C: one compact pass (defs -> sk, ties -> mixed tb; wave-aggregated LDS)
//   D: tie-select (per-level rank via level tag in k50), append to sk
//   E: counting sort (R8-verified) + decode
// LDS explicitly aliased: hist (80 KB) dies after B, overlaid by tb/aux/h/bs.
// ---------------------------------------------------------------------------
#define SORT_T 1024
__global__ __launch_bounds__(SORT_T)
void pipeline_kernel(const float* __restrict__ logits,
                     const float* __restrict__ reg,
                     const float* __restrict__ points,
                     float* __restrict__ sboxes,
                     float* __restrict__ sscores) {
#pragma clang fp contract(off)
    __shared__ __align__(16) char smem[131072];
    u64* sk   = (u64*)smem;                  //     0..32768 : 4096 u64 (persist)
    u32* hist = (u32*)(smem + 32768);        // 32768..114688: 5*4096 u32 (A/B)
    u64* tb   = (u64*)(smem + 32768);        // 32768..65536 : 4096 u64 (C/D)
    u64* aux  = (u64*)(smem + 65536);        // 65536..98304 : 4096 u64 (E)
    u32* h    = (u32*)(smem + 98304);        // 98304..114688: 4096 u32 (E)
    u32* bs   = (u32*)(smem + 114688);       // 114688..131072: 4096 u32 (E)
    __shared__ u32 sTl[NLEV], skkl[NLEV], wt[16];
    __shared__ u32 scnt, stcnt;

    const int b = blockIdx.x;
    const int tid = threadIdx.x;
    const int lane = tid & 63;
    const int wid = tid >> 6;
    const float* lg = logits + b * N_POINTS;

    // ---- Phase A: zero hist, one pass keys -> level histograms ----
    for (int i = tid; i < NLEV * NBIN; i += SORT_T) hist[i] = 0u;
    if (tid == 0) { scnt = 0u; stcnt = 0u; }
    __syncthreads();
    for (int i = tid; i < N_POINTS; i += SORT_T) {
        u32 key = sigkey(lg[i]);
        atomicAdd(&hist[level_of(i) * NBIN + ((key >> 19) & 4095u)], 1u);
    }
    __syncthreads();

    // ---- Phase B: 5 parallel selects (wave w handles level w) ----
    if (wid < NLEV) {
        const u32 K = (u32)k_of(wid);
        const u32* hh = hist + wid * NBIN;
        u32 S = 0;
#pragma unroll 8
        for (int i = 0; i < 64; ++i) S += hh[lane * 64 + i];
        u32 acc = S;
#pragma unroll
        for (int off = 1; off < 64; off <<= 1) {
            u32 v = (u32)__shfl_down((int)acc, off);
            if (lane + off < 64) acc += v;
        }
        u32 sfxAfter = acc - S;
        bool hit = (sfxAfter < K) && (sfxAfter + S >= K);
        u64 bal = __ballot(hit);
        int Lg = (int)__builtin_ctzll(bal);
        u32 sfxG = (u32)__shfl((int)sfxAfter, Lg);

        u32 v = hh[Lg * 64 + lane];
        u32 acc2 = v;
#pragma unroll
        for (int off = 1; off < 64; off <<= 1) {
            u32 t = (u32)__shfl_down((int)acc2, off);
            if (lane + off < 64) acc2 += t;
        }
        u32 sfx2 = sfxG + acc2 - v;
        bool hit2 = (sfx2 < K) && (sfx2 + v >= K);
        if (hit2) { sTl[wid] = (u32)(Lg * 64 + lane); skkl[wid] = K - sfx2; }
    }
    __syncthreads();                         // hist dead after this point

    // ---- Phase C: one compact pass over all points ----
    const u64 below = (lane == 0) ? 0ull : (~0ull >> (64 - lane));
    for (int i0 = tid; i0 - tid < N_POINTS; i0 += SORT_T) {
        bool active = i0 < N_POINTS;
        int pc = active ? i0 : (N_POINTS - 1);
        u32 key = sigkey(lg[pc]);
        int l = level_of(pc);
        u32 digit = (key >> 19) & 4095u;
        u32 T = sTl[l];
        bool isDef = active && (digit > T);
        bool isTie = active && (digit == T);
        u64 k50 = ((u64)key << 18) | ((u64)(7 - l) << 15)
                | (u64)(32767 - (pc - loff_of(l)));
        u64 grp = __ballot(isDef);
        if (grp) {
            int leader = (int)__builtin_ctzll(grp);
            u32 base_ = 0;
            if (lane == leader)
                base_ = atomicAdd(&scnt, (u32)__builtin_popcountll(grp));
            base_ = (u32)__shfl((int)base_, leader);
            if (isDef) sk[base_ + (u32)__builtin_popcountll(grp & below)] = k50;
        }
        u64 tg = __ballot(isTie);
        if (tg) {
            int leader = (int)__builtin_ctzll(tg);
            u32 base_ = 0;
            if (lane == leader)
                base_ = atomicAdd(&stcnt, (u32)__builtin_popcountll(tg));
            base_ = (u32)__shfl((int)base_, leader);
            if (isTie) {
                u32 pos = base_ + (u32)__builtin_popcountll(tg & below);
                if (pos < TIE_CAP) tb[pos] = k50;
            }
        }
    }
    __syncthreads();

    // ---- Phase D: tie-select (rank among same-level ties), append to sk ----
    int t = (int)stcnt; if (t > TIE_CAP) t = TIE_CAP;
    for (int j0 = tid; j0 - tid < t; j0 += SORT_T) {
        bool active = j0 < t;
        u64 kj = active ? tb[j0] : 0ull;
        u32 lvtag = (u32)(kj >> 15) & 7u;
        int r = 0;
        for (int i = 0; i < t; ++i) {
            u64 ki = tb[i];                   // broadcast read
            r += (ki > kj && (((u32)(ki >> 15) & 7u) == lvtag)) ? 1 : 0;
        }
        bool inc = active && (r < (int)skkl[7 - lvtag]);
        u64 grp = __ballot(inc);
        if (grp) {
            int leader = (int)__builtin_ctzll(grp);
            u32 base_ = 0;
            if (lane == leader)
                base_ = atomicAdd(&scnt, (u32)__builtin_popcountll(grp));
            base_ = (u32)__shfl((int)base_, leader);
            if (inc) sk[base_ + (u32)__builtin_popcountll(grp & below)] = kj;
        }
    }
    __syncthreads();
    const int total = (int)scnt;             // == 3500 by construction

    // ---- Phase E: counting sort by digit (desc) + exact intra-digit rank ----
    for (int i = tid; i < NBIN; i += SORT_T) h[i] = 0u;
    __syncthreads();
    for (int i = tid; i < total; i += SORT_T)
        atomicAdd(&h[(u32)(sk[i] >> 37) & 4095u], 1u);
    __syncthreads();

    u32 t0 = h[4095 - 4 * tid];
    u32 t1 = h[4095 - (4 * tid + 1)];
    u32 t2 = h[4095 - (4 * tid + 2)];
    u32 t3 = h[4095 - (4 * tid + 3)];
    u32 tsum = t0 + t1 + t2 + t3;
    u32 sc_ = tsum;
#pragma unroll
    for (int off = 1; off < 64; off <<= 1) {
        u32 v = (u32)__shfl_up((int)sc_, off);
        if (lane >= off) sc_ += v;
    }
    if (lane == 63) wt[wid] = sc_;
    __syncthreads();
    if (tid < 64) {
        u32 v = (tid < 16) ? wt[tid] : 0u;
        u32 s2 = v;
#pragma unroll
        for (int off = 1; off < 16; off <<= 1) {
            u32 x = (u32)__shfl_up((int)s2, off);
            if (tid >= off) s2 += x;
        }
        if (tid < 16) wt[tid] = s2 - v;      // exclusive wave offsets
    }
    __syncthreads();
    u32 run = (sc_ - tsum) + wt[wid];
    bs[4095 - 4 * tid] = run;       run += t0;
    bs[4095 - (4 * tid + 1)] = run; run += t1;
    bs[4095 - (4 * tid + 2)] = run; run += t2;
    bs[4095 - (4 * tid + 3)] = run;
    __syncthreads();
    for (int i = tid; i < NBIN; i += SORT_T) h[i] = 0u;
    __syncthreads();
    for (int i = tid; i < total; i += SORT_T) {
        u64 k = sk[i];
        u32 d = (u32)(k >> 37) & 4095u;
        u32 pos = bs[d] + atomicAdd(&h[d], 1u);
        aux[pos] = k;
    }
    __syncthreads();
    for (int p = tid; p < total; p += SORT_T) {
        u64 kp = aux[p];
        u32 d = (u32)(kp >> 37) & 4095u;
        u32 gbase = bs[d];
        u32 gend = (d == 0) ? (u32)total : bs[d - 1];
        u32 r = 0;
        for (u32 q = gbase; q < gend; ++q) r += (aux[q] > kp) ? 1u : 0u;
        sk[gbase + r] = kp;                  // unique keys -> exact slot
    }
    __syncthreads();

    // decode + write sorted candidates
    for (int r = tid; r < NCAND; r += SORT_T) {
        float x1 = 0.f, y1 = 0.f, x2 = 0.f, y2 = 0.f, sc = 0.f;
        if (r < total) {
            u64 k50 = sk[r];
            int lowb = (int)(k50 & 0x3FFFFull);
            int l = 7 - (lowb >> 15);
            int idxl = 32767 - (lowb & 32767);
            int p = loff_of(l) + idxl;
            u32 key32 = (u32)(k50 >> 18);
            sc = __uint_as_float(key32 ^ 0x80000000u);
            int gp = b * N_POINTS + p;
            float l_ = reg[gp * 4 + 0] * IMG;
            float t_ = reg[gp * 4 + 1] * IMG;
            float r_ = reg[gp * 4 + 2] * IMG;
            float bb = reg[gp * 4 + 3] * IMG;
            float px = points[p * 2 + 0];
            float py = points[p * 2 + 1];
            x1 = fminf(fmaxf(px - l_, 0.0f), IMG);
            y1 = fminf(fmaxf(py - t_, 0.0f), IMG);
            x2 = fminf(fmaxf(px + r_, 0.0f), IMG);
            y2 = fminf(fmaxf(py + bb, 0.0f), IMG);
        }
        int slot = b * NCAND + r;
        sboxes[slot * 4 + 0] = x1;
        sboxes[slot * 4 + 1] = y1;
        sboxes[slot * 4 + 2] = x2;
        sboxes[slot * 4 + 3] = y2;
        sscores[slot] = sc;
    }
}

// ---------------------------------------------------------------------------
// Kernel 3: suppression-mask matrix (R8 row-major + R11 f32-exact compare).
// ---------------------------------------------------------------------------
__global__ __launch_bounds__(256)
void mask_kernel(const float* __restrict__ sboxes,
                 const float* __restrict__ sscores,
                 u64* __restrict__ mask,
                 u64* __restrict__ diag) {
#pragma clang fp contract(off)
    const int b = blockIdx.y;
    const int wv = threadIdx.x >> 6;
    const int lane = threadIdx.x & 63;
    const int NG = (NCAND + 3) >> 2;             // 875 row-groups
    const int gidx = blockIdx.x * 4 + wv;
    if (gidx >= NG) return;
    const int c0 = gidx << 2;

    const float4* gb = (const float4*)sboxes + b * NCAND;
    const float* gs = sscores + b * NCAND;
    u64* mout = mask + (size_t)b * MASK_STRIDE;
    u64* dout = diag + (size_t)b * DIAG_STRIDE;

    float4 bc[4]; float a1[4]; bool ok[4]; int g[4]; u64* rp[4];
    bool any = false;
#pragma unroll
    for (int i = 0; i < 4; ++i) {
        int c = c0 + i;
        int cc = (c < NCAND) ? c : (NCAND - 1);
        bc[i] = gb[cc];
        a1[i] = (bc[i].z - bc[i].x) * (bc[i].w - bc[i].y);
        ok[i] = (c < NCAND) && (gs[cc] > SCORE_TH);
        g[i] = cc >> 6;
        rp[i] = mout + mask_off(cc) - g[i];
        any |= ok[i];
    }
    if (!any) return;                            // wave-uniform

    for (int w = (c0 >> 6); w < 55; ++w) {
        int cj = (w << 6) + lane;
        float4 bj = (cj < NCAND) ? gb[cj] : make_float4(0.f, 0.f, 0.f, 0.f);
        float a2 = (bj.z - bj.x) * (bj.w - bj.y);
#pragma unroll
        for (int i = 0; i < 4; ++i) {
            float x1 = fmaxf(bc[i].x, bj.x);
            float y1 = fmaxf(bc[i].y, bj.y);
            float x2 = fminf(bc[i].z, bj.z);
            float y2 = fminf(bc[i].w, bj.w);
            float inter = fmaxf(x2 - x1, 0.f) * fmaxf(y2 - y1, 0.f);
            float denom = a1[i] + a2 - inter + 1e-9f;   // ref association
            float hf = 0.5f * denom;                    // exact
            float rr = fmaf(0x1p-25f, denom, hf);       // RN(T)
            u64 bits = __ballot(inter > rr);
            u64 eq = __ballot(inter == rr);
            if (eq) {                                   // boundary: exact f64
                u64 fb = __ballot((double)inter > MTH * (double)denom);
                bits |= (eq & fb);
            }
            if (lane == 0 && ok[i] && w >= g[i]) {
                rp[i][w] = bits;
                if (w == g[i]) dout[c0 + i] = bits;     // dense diagonal copy
            }
        }
    }
}

// ---------------------------------------------------------------------------
// Kernel 4: sorted-order NMS scan (R10-verified: diag prefetch, self-store).
// ---------------------------------------------------------------------------
__global__ __launch_bounds__(64)
void scan_kernel(const float* __restrict__ sboxes,
                 const float* __restrict__ sscores,
                 const u64* __restrict__ mask,
                 const u64* __restrict__ diag,
                 float* __restrict__ out) {
    const int b = blockIdx.x;
    const int lane = threadIdx.x;            // 64 threads = 1 wave
    const float4* gb = (const float4*)sboxes + b * NCAND;
    const float* gs = sscores + b * NCAND;
    const u64* mrow = mask + (size_t)b * MASK_STRIDE;
    const u64* drow = diag + (size_t)b * DIAG_STRIDE;

    float* ob = out + OUT_BOXES  + b * MAX_DET * 4;
    float* os = out + OUT_SCORES + b * MAX_DET;
    float* ol = out + OUT_LABELS + b * MAX_DET;
    float* ov = out + OUT_VALID  + b * MAX_DET;

    u64 m = 0ull;                            // lane f owns future-word f
    u64 rowN = drow[lane];                   // contiguous diagonal prefetch
    float4 bjN = gb[lane];
    float sjN = gs[lane];

    int kept = 0;
    for (int w = 0; w < 55; ++w) {
        const int wbase = w << 6;
        const u64 row = rowN;
        const float4 bj = bjN;
        const float sj = sjN;
        if (w < 54) {                        // prefetch next word (contiguous)
            int cn = wbase + 64 + lane;
            int cc = (cn < NCAND) ? cn : (NCAND - 1);
            rowN = drow[cc];
            bjN = gb[cc];
            float s = gs[cc];
            sjN = (cn < NCAND) ? s : 0.f;
        }
        int c = wbase + lane;
        u64 bad = __ballot(!((c < NCAND) && (sj > SCORE_TH)));
        u64 cur = readlane64(m, w) | bad;
        u64 km = 0ull;
        while (kept < MAX_DET) {
            u64 avail = ~cur;
            if (avail == 0ull) break;
            int t = (int)__builtin_ctzll(avail);       // uniform
            u64 r = readlane64(row, t);                // keep t's intra bits
            cur |= r | (1ull << t);
            km |= 1ull << t;
            if (lane == t) {
                ob[kept * 4 + 0] = bj.x;
                ob[kept * 4 + 1] = bj.y;
                ob[kept * 4 + 2] = bj.z;
                ob[kept * 4 + 3] = bj.w;
                os[kept] = sj;
                ol[kept] = 0.0f;
                ov[kept] = 1.0f;
            }
            kept++;
        }
        if (km) {
            const bool lr = (lane >= w && lane < 55);
            const int lo = lane - w;
            u64 acc = 0ull;
            while (km) {
#define POPBIT(tn) int tn = -1; if (km) { tn = (int)__builtin_ctzll(km); km &= km - 1ull; }
                POPBIT(t0) POPBIT(t1) POPBIT(t2) POPBIT(t3)
                POPBIT(t4) POPBIT(t5) POPBIT(t6) POPBIT(t7)
#undef POPBIT
                u64 v0 = 0, v1 = 0, v2 = 0, v3 = 0, v4 = 0, v5 = 0, v6 = 0, v7 = 0;
                if (lr) {
                    v0 = mrow[mask_off(wbase + t0) + lo];
                    if (t1 >= 0) v1 = mrow[mask_off(wbase + t1) + lo];
                    if (t2 >= 0) v2 = mrow[mask_off(wbase + t2) + lo];
                    if (t3 >= 0) v3 = mrow[mask_off(wbase + t3) + lo];
                    if (t4 >= 0) v4 = mrow[mask_off(wbase + t4) + lo];
                    if (t5 >= 0) v5 = mrow[mask_off(wbase + t5) + lo];
                    if (t6 >= 0) v6 = mrow[mask_off(wbase + t6) + lo];
                    if (t7 >= 0) v7 = mrow[mask_off(wbase + t7) + lo];
                }
                acc |= ((v0 | v1) | (v2 | v3)) | ((v4 | v5) | (v6 | v7));
            }
            m |= acc;
        }
        if (kept >= MAX_DET) break;
    }
    for (int k = kept + lane; k < MAX_DET; k += 64) {
        ob[k * 4 + 0] = 0.f; ob[k * 4 + 1] = 0.f;
        ob[k * 4 + 2] = 0.f; ob[k * 4 + 3] = 0.f;
        os[k] = 0.f; ol[k] = -1.f; ov[k] = 0.f;
    }
}

// ---------------------------------------------------------------------------
extern "C" void kernel_launch(void* const* d_in, const int* in_sizes, int n_in,
                              void* d_out, int out_size, void* d_ws, size_t ws_size,
                              hipStream_t stream) {
    const float* points = (const float*)d_in[0];
    const float* gt     = (const float*)d_in[1];
    const float* logits = (const float*)d_in[2];
    const float* reg    = (const float*)d_in[3];
    float* out = (float*)d_out;

    float* sboxes  = (float*)((char*)d_ws + WS_SBOX);
    float* sscores = (float*)((char*)d_ws + WS_SSC);
    u64* mask   = (u64*)((char*)d_ws + WS_MASK);
    u64* diag   = (u64*)((char*)d_ws + WS_DIAG);

    pipeline_kernel<<<BATCH, SORT_T, 0, stream>>>(logits, reg, points,
                                                  sboxes, sscores);

    dim3 g1((N_POINTS + 256 * MPT - 1) / (256 * MPT), BATCH);
    match_kernel<<<g1, 256, 0, stream>>>(points, gt, out + OUT_MATCH);

    dim3 g5(((NCAND + 3) / 4 + 3) / 4, BATCH);   // 219 x 8 blocks, 4 rows/wave
    mask_kernel<<<g5, 256, 0, stream>>>(sboxes, sscores, mask, diag);

    scan_kernel<<<BATCH, 64, 0, stream>>>(sboxes, sscores, mask, diag, out);
}

// Round 13
// 263.866 us; speedup vs baseline: 1.0609x; 1.0609x over previous
//
#include <hip/hip_runtime.h>
#include <stdint.h>

// Problem constants
#define N_POINTS   34100
#define BATCH      8
#define N_GT       200
#define NLEV       5
#define NCAND      3500
#define MAX_DET    300
#define SCORE_TH   0.05f
#define NMS_TH     0.5f
#define IMG        1280.0f
#define NBIN       4096
#define TIE_CAP    4096
// Exact threshold: RN(inter/denom) > 0.5  <=>  inter > T, T=(0.5+2^-25)*denom
// f32 fast path + f64 boundary fallback (R11-verified, absmax 0).
#define MTH 0.50000002980232238769531250

// Output layout (float32 flat, reference return order)
#define OUT_MATCH  0        // 8*34100
#define OUT_BOXES  272800   // 8*300*4
#define OUT_SCORES 282400   // 8*300
#define OUT_LABELS 284800   // 8*300
#define OUT_VALID  287200   // 8*300

// Workspace layout (bytes)
#define WS_KEYS    0              // u32[8*34100]   = 1,091,200 (restored R13)
#define WS_SBOX    2632192        // float4[8*3500] =   448,000
#define WS_SSC     3080192        // float[8*3500]  =   112,000
#define WS_MASK    3192192        // u64[8*98560]   = 6,307,840
#define WS_DIAG    9500032        // u64[8*3520]    =   225,280
#define MASK_STRIDE 98560
#define DIAG_STRIDE 3520

typedef unsigned long long u64;
typedef uint32_t u32;

// Packed upper-triangle row offset: row c stores words (c>>6)..54
__device__ __forceinline__ int mask_off(int c) {
    int g = c >> 6;
    return 64 * (55 * g - (g * (g - 1)) / 2) + (c - (g << 6)) * (55 - g);
}

__device__ __forceinline__ int level_of(int p) {
    return (p < 25600) ? 0 : (p < 32000) ? 1 : (p < 33600) ? 2 : (p < 34000) ? 3 : 4;
}
__device__ __forceinline__ int loff_of(int l) {
    return (l == 0) ? 0 : (l == 1) ? 25600 : (l == 2) ? 32000 : (l == 3) ? 33600 : 34000;
}
__device__ __forceinline__ int k_of(int l) {
    return (l == 0) ? 1000 : (l == 1) ? 1000 : (l == 2) ? 1000 : (l == 3) ? 400 : 100;
}
__device__ __forceinline__ u64 readlane64(u64 v, int t) {
    u32 lo = (u32)__builtin_amdgcn_readlane((int)(u32)v, t);
    u32 hi = (u32)__builtin_amdgcn_readlane((int)(u32)(v >> 32), t);
    return ((u64)hi << 32) | lo;
}

// ---------------------------------------------------------------------------
// Kernel 1: point->gt matching + sigmoid sortable key (R11-verified; keys
// computed here at 536-block parallelism — R12 recomputed sigmoid twice at
// 8-block parallelism inside pipeline, a wash; this undoes that).
// ---------------------------------------------------------------------------
#define MPT 2
__global__ __launch_bounds__(256)
void match_key_kernel(const float* __restrict__ points,
                      const float* __restrict__ gt,
                      const float* __restrict__ logits,
                      float* __restrict__ out_match,
                      u32* __restrict__ keys) {
#pragma clang fp contract(off)
    __shared__ float bx1[N_GT], by1[N_GT], bx2[N_GT], by2[N_GT], ar[N_GT];
    const int b = blockIdx.y;
    const int base = blockIdx.x * (256 * MPT) + threadIdx.x;

    for (int j = threadIdx.x; j < N_GT; j += 256) {
        float x1 = gt[(b * N_GT + j) * 4 + 0];
        float y1 = gt[(b * N_GT + j) * 4 + 1];
        float x2 = gt[(b * N_GT + j) * 4 + 2];
        float y2 = gt[(b * N_GT + j) * 4 + 3];
        bx1[j] = x1; by1[j] = y1; bx2[j] = x2; by2[j] = y2;
        ar[j] = (x2 - x1) * (y2 - y1);
    }
    __syncthreads();

    const float BIGF = 2147483648.0f;   // float32(2^31-1) rounds to 2^31
    float px[MPT], py[MPT], best[MPT];
    int bi[MPT];
#pragma unroll
    for (int k = 0; k < MPT; ++k) {
        int p = base + k * 256;
        int pc = (p < N_POINTS) ? p : 0;
        px[k] = points[pc * 2 + 0];
        py[k] = points[pc * 2 + 1];
        best[k] = BIGF; bi[k] = -1;
    }
    for (int j = 0; j < N_GT; ++j) {
        float x1 = bx1[j], y1 = by1[j], x2 = bx2[j], y2 = by2[j], a = ar[j];
#pragma unroll
        for (int k = 0; k < MPT; ++k) {
            bool inside = (px[k] >= x1) && (px[k] <= x2) &&
                          (py[k] >= y1) && (py[k] <= y2);
            float cost = inside ? a : BIGF;
            if (cost < best[k]) { best[k] = cost; bi[k] = j; }   // strict <
        }
    }
#pragma unroll
    for (int k = 0; k < MPT; ++k) {
        int p = base + k * 256;
        if (p >= N_POINTS) continue;
        out_match[b * N_POINTS + p] = (float)bi[k];
        float lg = logits[b * N_POINTS + p];
        float s = 1.0f / (1.0f + expf(-lg));
        u32 u = __float_as_uint(s);
        u32 key = (u & 0x80000000u) ? ~u : (u | 0x80000000u);
        keys[b * N_POINTS + p] = key;
    }
}

// ---------------------------------------------------------------------------
// Kernel 2: R13 pipeline — R12's single-pass phases, reading precomputed keys:
//   A: one pass over keys -> 5 level-histograms (LDS)
//   B: 5 threshold selects in PARALLEL (waves 0..4)
//   C: one compact pass (defs -> sk, ties -> mixed tb; wave-aggregated LDS)
//   D: tie-select (per-level rank via level tag in k50), append to sk
//   E: counting sort (R8-verified) + decode
// ---------------------------------------------------------------------------
#define SORT_T 1024
__global__ __launch_bounds__(SORT_T)
void pipeline_kernel(const u32* __restrict__ keys,
                     const float* __restrict__ reg,
                     const float* __restrict__ points,
                     float* __restrict__ sboxes,
                     float* __restrict__ sscores) {
#pragma clang fp contract(off)
    __shared__ __align__(16) char smem[131072];
    u64* sk   = (u64*)smem;                  //     0..32768 : 4096 u64 (persist)
    u32* hist = (u32*)(smem + 32768);        // 32768..114688: 5*4096 u32 (A/B)
    u64* tb   = (u64*)(smem + 32768);        // 32768..65536 : 4096 u64 (C/D)
    u64* aux  = (u64*)(smem + 65536);        // 65536..98304 : 4096 u64 (E)
    u32* h    = (u32*)(smem + 98304);        // 98304..114688: 4096 u32 (E)
    u32* bs   = (u32*)(smem + 114688);       // 114688..131072: 4096 u32 (E)
    __shared__ u32 sTl[NLEV], skkl[NLEV], wt[16];
    __shared__ u32 scnt, stcnt;

    const int b = blockIdx.x;
    const int tid = threadIdx.x;
    const int lane = tid & 63;
    const int wid = tid >> 6;
    const u32* kk_ = keys + b * N_POINTS;

    // ---- Phase A: zero hist, one pass keys -> level histograms ----
    for (int i = tid; i < NLEV * NBIN; i += SORT_T) hist[i] = 0u;
    if (tid == 0) { scnt = 0u; stcnt = 0u; }
    __syncthreads();
    for (int i = tid; i < N_POINTS; i += SORT_T) {
        u32 key = kk_[i];
        atomicAdd(&hist[level_of(i) * NBIN + ((key >> 19) & 4095u)], 1u);
    }
    __syncthreads();

    // ---- Phase B: 5 parallel selects (wave w handles level w) ----
    if (wid < NLEV) {
        const u32 K = (u32)k_of(wid);
        const u32* hh = hist + wid * NBIN;
        u32 S = 0;
#pragma unroll 8
        for (int i = 0; i < 64; ++i) S += hh[lane * 64 + i];
        u32 acc = S;
#pragma unroll
        for (int off = 1; off < 64; off <<= 1) {
            u32 v = (u32)__shfl_down((int)acc, off);
            if (lane + off < 64) acc += v;
        }
        u32 sfxAfter = acc - S;
        bool hit = (sfxAfter < K) && (sfxAfter + S >= K);
        u64 bal = __ballot(hit);
        int Lg = (int)__builtin_ctzll(bal);
        u32 sfxG = (u32)__shfl((int)sfxAfter, Lg);

        u32 v = hh[Lg * 64 + lane];
        u32 acc2 = v;
#pragma unroll
        for (int off = 1; off < 64; off <<= 1) {
            u32 t = (u32)__shfl_down((int)acc2, off);
            if (lane + off < 64) acc2 += t;
        }
        u32 sfx2 = sfxG + acc2 - v;
        bool hit2 = (sfx2 < K) && (sfx2 + v >= K);
        if (hit2) { sTl[wid] = (u32)(Lg * 64 + lane); skkl[wid] = K - sfx2; }
    }
    __syncthreads();                         // hist dead after this point

    // ---- Phase C: one compact pass over all points ----
    const u64 below = (lane == 0) ? 0ull : (~0ull >> (64 - lane));
    for (int i0 = tid; i0 - tid < N_POINTS; i0 += SORT_T) {
        bool active = i0 < N_POINTS;
        int pc = active ? i0 : (N_POINTS - 1);
        u32 key = kk_[pc];
        int l = level_of(pc);
        u32 digit = (key >> 19) & 4095u;
        u32 T = sTl[l];
        bool isDef = active && (digit > T);
        bool isTie = active && (digit == T);
        u64 k50 = ((u64)key << 18) | ((u64)(7 - l) << 15)
                | (u64)(32767 - (pc - loff_of(l)));
        u64 grp = __ballot(isDef);
        if (grp) {
            int leader = (int)__builtin_ctzll(grp);
            u32 base_ = 0;
            if (lane == leader)
                base_ = atomicAdd(&scnt, (u32)__builtin_popcountll(grp));
            base_ = (u32)__shfl((int)base_, leader);
            if (isDef) sk[base_ + (u32)__builtin_popcountll(grp & below)] = k50;
        }
        u64 tg = __ballot(isTie);
        if (tg) {
            int leader = (int)__builtin_ctzll(tg);
            u32 base_ = 0;
            if (lane == leader)
                base_ = atomicAdd(&stcnt, (u32)__builtin_popcountll(tg));
            base_ = (u32)__shfl((int)base_, leader);
            if (isTie) {
                u32 pos = base_ + (u32)__builtin_popcountll(tg & below);
                if (pos < TIE_CAP) tb[pos] = k50;
            }
        }
    }
    __syncthreads();

    // ---- Phase D: tie-select (rank among same-level ties), append to sk ----
    int t = (int)stcnt; if (t > TIE_CAP) t = TIE_CAP;
    for (int j0 = tid; j0 - tid < t; j0 += SORT_T) {
        bool active = j0 < t;
        u64 kj = active ? tb[j0] : 0ull;
        u32 lvtag = (u32)(kj >> 15) & 7u;
        int r = 0;
        for (int i = 0; i < t; ++i) {
            u64 ki = tb[i];                   // broadcast read
            r += (ki > kj && (((u32)(ki >> 15) & 7u) == lvtag)) ? 1 : 0;
        }
        bool inc = active && (r < (int)skkl[7 - lvtag]);
        u64 grp = __ballot(inc);
        if (grp) {
            int leader = (int)__builtin_ctzll(grp);
            u32 base_ = 0;
            if (lane == leader)
                base_ = atomicAdd(&scnt, (u32)__builtin_popcountll(grp));
            base_ = (u32)__shfl((int)base_, leader);
            if (inc) sk[base_ + (u32)__builtin_popcountll(grp & below)] = kj;
        }
    }
    __syncthreads();
    const int total = (int)scnt;             // == 3500 by construction

    // ---- Phase E: counting sort by digit (desc) + exact intra-digit rank ----
    for (int i = tid; i < NBIN; i += SORT_T) h[i] = 0u;
    __syncthreads();
    for (int i = tid; i < total; i += SORT_T)
        atomicAdd(&h[(u32)(sk[i] >> 37) & 4095u], 1u);
    __syncthreads();

    u32 t0 = h[4095 - 4 * tid];
    u32 t1 = h[4095 - (4 * tid + 1)];
    u32 t2 = h[4095 - (4 * tid + 2)];
    u32 t3 = h[4095 - (4 * tid + 3)];
    u32 tsum = t0 + t1 + t2 + t3;
    u32 sc_ = tsum;
#pragma unroll
    for (int off = 1; off < 64; off <<= 1) {
        u32 v = (u32)__shfl_up((int)sc_, off);
        if (lane >= off) sc_ += v;
    }
    if (lane == 63) wt[wid] = sc_;
    __syncthreads();
    if (tid < 64) {
        u32 v = (tid < 16) ? wt[tid] : 0u;
        u32 s2 = v;
#pragma unroll
        for (int off = 1; off < 16; off <<= 1) {
            u32 x = (u32)__shfl_up((int)s2, off);
            if (tid >= off) s2 += x;
        }
        if (tid < 16) wt[tid] = s2 - v;      // exclusive wave offsets
    }
    __syncthreads();
    u32 run = (sc_ - tsum) + wt[wid];
    bs[4095 - 4 * tid] = run;       run += t0;
    bs[4095 - (4 * tid + 1)] = run; run += t1;
    bs[4095 - (4 * tid + 2)] = run; run += t2;
    bs[4095 - (4 * tid + 3)] = run;
    __syncthreads();
    for (int i = tid; i < NBIN; i += SORT_T) h[i] = 0u;
    __syncthreads();
    for (int i = tid; i < total; i += SORT_T) {
        u64 k = sk[i];
        u32 d = (u32)(k >> 37) & 4095u;
        u32 pos = bs[d] + atomicAdd(&h[d], 1u);
        aux[pos] = k;
    }
    __syncthreads();
    for (int p = tid; p < total; p += SORT_T) {
        u64 kp = aux[p];
        u32 d = (u32)(kp >> 37) & 4095u;
        u32 gbase = bs[d];
        u32 gend = (d == 0) ? (u32)total : bs[d - 1];
        u32 r = 0;
        for (u32 q = gbase; q < gend; ++q) r += (aux[q] > kp) ? 1u : 0u;
        sk[gbase + r] = kp;                  // unique keys -> exact slot
    }
    __syncthreads();

    // decode + write sorted candidates
    for (int r = tid; r < NCAND; r += SORT_T) {
        float x1 = 0.f, y1 = 0.f, x2 = 0.f, y2 = 0.f, sc = 0.f;
        if (r < total) {
            u64 k50 = sk[r];
            int lowb = (int)(k50 & 0x3FFFFull);
            int l = 7 - (lowb >> 15);
            int idxl = 32767 - (lowb & 32767);
            int p = loff_of(l) + idxl;
            u32 key32 = (u32)(k50 >> 18);
            sc = __uint_as_float(key32 ^ 0x80000000u);
            int gp = b * N_POINTS + p;
            float l_ = reg[gp * 4 + 0] * IMG;
            float t_ = reg[gp * 4 + 1] * IMG;
            float r_ = reg[gp * 4 + 2] * IMG;
            float bb = reg[gp * 4 + 3] * IMG;
            float px = points[p * 2 + 0];
            float py = points[p * 2 + 1];
            x1 = fminf(fmaxf(px - l_, 0.0f), IMG);
            y1 = fminf(fmaxf(py - t_, 0.0f), IMG);
            x2 = fminf(fmaxf(px + r_, 0.0f), IMG);
            y2 = fminf(fmaxf(py + bb, 0.0f), IMG);
        }
        int slot = b * NCAND + r;
        sboxes[slot * 4 + 0] = x1;
        sboxes[slot * 4 + 1] = y1;
        sboxes[slot * 4 + 2] = x2;
        sboxes[slot * 4 + 3] = y2;
        sscores[slot] = sc;
    }
}

// ---------------------------------------------------------------------------
// Kernel 3: suppression-mask matrix. R13: LOAD-BALANCED — each wave handles
// row-group g AND its mirror NG-1-g, so per-wave word-iterations are ~constant
// (~56) instead of 55..1 (R10 showed 28% occupancy from the long-block tail).
// Row-major stores + R11 f32-exact compare retained.
// ---------------------------------------------------------------------------
__global__ __launch_bounds__(256)
void mask_kernel(const float* __restrict__ sboxes,
                 const float* __restrict__ sscores,
                 u64* __restrict__ mask,
                 u64* __restrict__ diag) {
#pragma clang fp contract(off)
    const int b = blockIdx.y;
    const int wv = threadIdx.x >> 6;
    const int lane = threadIdx.x & 63;
    const int NG = (NCAND + 3) >> 2;             // 875 row-groups
    const int NH = (NG + 1) >> 1;                // 438 balanced pairs
    const int gidx = blockIdx.x * 4 + wv;
    if (gidx >= NH) return;

    const float4* gb = (const float4*)sboxes + b * NCAND;
    const float* gs = sscores + b * NCAND;
    u64* mout = mask + (size_t)b * MASK_STRIDE;
    u64* dout = diag + (size_t)b * DIAG_STRIDE;

    for (int s = 0; s < 2; ++s) {
        const int g0 = (s == 0) ? gidx : (NG - 1 - gidx);
        if (s == 1 && g0 == gidx) break;         // odd middle processed once
        const int c0 = g0 << 2;

        float4 bc[4]; float a1[4]; bool ok[4]; int g[4]; u64* rp[4];
        bool any = false;
#pragma unroll
        for (int i = 0; i < 4; ++i) {
            int c = c0 + i;
            int cc = (c < NCAND) ? c : (NCAND - 1);
            bc[i] = gb[cc];
            a1[i] = (bc[i].z - bc[i].x) * (bc[i].w - bc[i].y);
            ok[i] = (c < NCAND) && (gs[cc] > SCORE_TH);
            g[i] = cc >> 6;
            rp[i] = mout + mask_off(cc) - g[i];
            any |= ok[i];
        }
        if (!any) continue;                      // wave-uniform

        for (int w = (c0 >> 6); w < 55; ++w) {
            int cj = (w << 6) + lane;
            float4 bj = (cj < NCAND) ? gb[cj] : make_float4(0.f, 0.f, 0.f, 0.f);
            float a2 = (bj.z - bj.x) * (bj.w - bj.y);
#pragma unroll
            for (int i = 0; i < 4; ++i) {
                float x1 = fmaxf(bc[i].x, bj.x);
                float y1 = fmaxf(bc[i].y, bj.y);
                float x2 = fminf(bc[i].z, bj.z);
                float y2 = fminf(bc[i].w, bj.w);
                float inter = fmaxf(x2 - x1, 0.f) * fmaxf(y2 - y1, 0.f);
                float denom = a1[i] + a2 - inter + 1e-9f;   // ref association
                float hf = 0.5f * denom;                    // exact
                float rr = fmaf(0x1p-25f, denom, hf);       // RN(T)
                u64 bits = __ballot(inter > rr);
                u64 eq = __ballot(inter == rr);
                if (eq) {                                   // boundary: exact f64
                    u64 fb = __ballot((double)inter > MTH * (double)denom);
                    bits |= (eq & fb);
                }
                if (lane == 0 && ok[i] && w >= g[i]) {
                    rp[i][w] = bits;
                    if (w == g[i]) dout[c0 + i] = bits;     // dense diagonal
                }
            }
        }
    }
}

// ---------------------------------------------------------------------------
// Kernel 4: sorted-order NMS scan (R10-verified: diag prefetch, self-store).
// ---------------------------------------------------------------------------
__global__ __launch_bounds__(64)
void scan_kernel(const float* __restrict__ sboxes,
                 const float* __restrict__ sscores,
                 const u64* __restrict__ mask,
                 const u64* __restrict__ diag,
                 float* __restrict__ out) {
    const int b = blockIdx.x;
    const int lane = threadIdx.x;            // 64 threads = 1 wave
    const float4* gb = (const float4*)sboxes + b * NCAND;
    const float* gs = sscores + b * NCAND;
    const u64* mrow = mask + (size_t)b * MASK_STRIDE;
    const u64* drow = diag + (size_t)b * DIAG_STRIDE;

    float* ob = out + OUT_BOXES  + b * MAX_DET * 4;
    float* os = out + OUT_SCORES + b * MAX_DET;
    float* ol = out + OUT_LABELS + b * MAX_DET;
    float* ov = out + OUT_VALID  + b * MAX_DET;

    u64 m = 0ull;                            // lane f owns future-word f
    u64 rowN = drow[lane];                   // contiguous diagonal prefetch
    float4 bjN = gb[lane];
    float sjN = gs[lane];

    int kept = 0;
    for (int w = 0; w < 55; ++w) {
        const int wbase = w << 6;
        const u64 row = rowN;
        const float4 bj = bjN;
        const float sj = sjN;
        if (w < 54) {                        // prefetch next word (contiguous)
            int cn = wbase + 64 + lane;
            int cc = (cn < NCAND) ? cn : (NCAND - 1);
            rowN = drow[cc];
            bjN = gb[cc];
            float s = gs[cc];
            sjN = (cn < NCAND) ? s : 0.f;
        }
        int c = wbase + lane;
        u64 bad = __ballot(!((c < NCAND) && (sj > SCORE_TH)));
        u64 cur = readlane64(m, w) | bad;
        u64 km = 0ull;
        while (kept < MAX_DET) {
            u64 avail = ~cur;
            if (avail == 0ull) break;
            int t = (int)__builtin_ctzll(avail);       // uniform
            u64 r = readlane64(row, t);                // keep t's intra bits
            cur |= r | (1ull << t);
            km |= 1ull << t;
            if (lane == t) {
                ob[kept * 4 + 0] = bj.x;
                ob[kept * 4 + 1] = bj.y;
                ob[kept * 4 + 2] = bj.z;
                ob[kept * 4 + 3] = bj.w;
                os[kept] = sj;
                ol[kept] = 0.0f;
                ov[kept] = 1.0f;
            }
            kept++;
        }
        if (km) {
            const bool lr = (lane >= w && lane < 55);
            const int lo = lane - w;
            u64 acc = 0ull;
            while (km) {
#define POPBIT(tn) int tn = -1; if (km) { tn = (int)__builtin_ctzll(km); km &= km - 1ull; }
                POPBIT(t0) POPBIT(t1) POPBIT(t2) POPBIT(t3)
                POPBIT(t4) POPBIT(t5) POPBIT(t6) POPBIT(t7)
#undef POPBIT
                u64 v0 = 0, v1 = 0, v2 = 0, v3 = 0, v4 = 0, v5 = 0, v6 = 0, v7 = 0;
                if (lr) {
                    v0 = mrow[mask_off(wbase + t0) + lo];
                    if (t1 >= 0) v1 = mrow[mask_off(wbase + t1) + lo];
                    if (t2 >= 0) v2 = mrow[mask_off(wbase + t2) + lo];
                    if (t3 >= 0) v3 = mrow[mask_off(wbase + t3) + lo];
                    if (t4 >= 0) v4 = mrow[mask_off(wbase + t4) + lo];
                    if (t5 >= 0) v5 = mrow[mask_off(wbase + t5) + lo];
                    if (t6 >= 0) v6 = mrow[mask_off(wbase + t6) + lo];
                    if (t7 >= 0) v7 = mrow[mask_off(wbase + t7) + lo];
                }
                acc |= ((v0 | v1) | (v2 | v3)) | ((v4 | v5) | (v6 | v7));
            }
            m |= acc;
        }
        if (kept >= MAX_DET) break;
    }
    for (int k = kept + lane; k < MAX_DET; k += 64) {
        ob[k * 4 + 0] = 0.f; ob[k * 4 + 1] = 0.f;
        ob[k * 4 + 2] = 0.f; ob[k * 4 + 3] = 0.f;
        os[k] = 0.f; ol[k] = -1.f; ov[k] = 0.f;
    }
}

// ---------------------------------------------------------------------------
extern "C" void kernel_launch(void* const* d_in, const int* in_sizes, int n_in,
                              void* d_out, int out_size, void* d_ws, size_t ws_size,
                              hipStream_t stream) {
    const float* points = (const float*)d_in[0];
    const float* gt     = (const float*)d_in[1];
    const float* logits = (const float*)d_in[2];
    const float* reg    = (const float*)d_in[3];
    float* out = (float*)d_out;

    u32* keys      = (u32*)((char*)d_ws + WS_KEYS);
    float* sboxes  = (float*)((char*)d_ws + WS_SBOX);
    float* sscores = (float*)((char*)d_ws + WS_SSC);
    u64* mask   = (u64*)((char*)d_ws + WS_MASK);
    u64* diag   = (u64*)((char*)d_ws + WS_DIAG);

    dim3 g1((N_POINTS + 256 * MPT - 1) / (256 * MPT), BATCH);
    match_key_kernel<<<g1, 256, 0, stream>>>(points, gt, logits,
                                             out + OUT_MATCH, keys);

    pipeline_kernel<<<BATCH, SORT_T, 0, stream>>>(keys, reg, points,
                                                  sboxes, sscores);

    dim3 g5((((NCAND + 3) / 4 + 1) / 2 + 3) / 4, BATCH);  // 110 x 8, balanced
    mask_kernel<<<g5, 256, 0, stream>>>(sboxes, sscores, mask, diag);

    scan_kernel<<<BATCH, 64, 0, stream>>>(sboxes, sscores, mask, diag, out);
}